// Round 2
// baseline (2819.999 us; speedup 1.0000x reference)
//
#include <hip/hip_runtime.h>
#include <math.h>

#define S_LEN 2048
#define D_MODEL 1024
#define N_BATCH 4
#define N_HALF 512

// ============================================================
// Tiled fp32 GEMM, C[M,N] = A[M,K] * B[N,K]^T (+bias), batched over blockIdx.z
// 64x64 block tile, 4x4 per-thread micro-tile, BK=16.
// LDS pad +4 keeps rows 16B-aligned for ds_read_b128 (2-way bank alias is free).
// ============================================================
__global__ __launch_bounds__(256)
void gemm_nt(const float* __restrict__ A, const float* __restrict__ B,
             const float* __restrict__ bias, float* __restrict__ C,
             int M, int N, int K,
             long long sA, long long sB, long long sC) {
  __shared__ float As[16][68];
  __shared__ float Bs[16][68];
  const int tid = threadIdx.x;
  const int tx = tid & 15, ty = tid >> 4;
  const int bm = blockIdx.y * 64, bn = blockIdx.x * 64;
  const long long z = blockIdx.z;
  A += z * sA; B += z * sB; C += z * sC;
  const int lr = tid >> 2;          // 0..63
  const int lk = (tid & 3) << 2;    // 0,4,8,12
  const float* Ap = A + (long long)(bm + lr) * K + lk;
  const float* Bp = B + (long long)(bn + lr) * K + lk;
  float acc[4][4] = {};
  for (int k0 = 0; k0 < K; k0 += 16) {
    float4 a4 = *(const float4*)(Ap + k0);
    float4 b4 = *(const float4*)(Bp + k0);
    As[lk+0][lr]=a4.x; As[lk+1][lr]=a4.y; As[lk+2][lr]=a4.z; As[lk+3][lr]=a4.w;
    Bs[lk+0][lr]=b4.x; Bs[lk+1][lr]=b4.y; Bs[lk+2][lr]=b4.z; Bs[lk+3][lr]=b4.w;
    __syncthreads();
#pragma unroll
    for (int kk = 0; kk < 16; kk++) {
      float4 a = *(const float4*)&As[kk][ty*4];
      float4 b = *(const float4*)&Bs[kk][tx*4];
      float ar[4] = {a.x, a.y, a.z, a.w};
      float br[4] = {b.x, b.y, b.z, b.w};
#pragma unroll
      for (int i = 0; i < 4; i++)
#pragma unroll
        for (int j = 0; j < 4; j++)
          acc[i][j] += ar[i] * br[j];
    }
    __syncthreads();
  }
  float4 bia = make_float4(0.f, 0.f, 0.f, 0.f);
  if (bias) bia = *(const float4*)(bias + bn + tx*4);
#pragma unroll
  for (int i = 0; i < 4; i++) {
    float4 o;
    o.x = acc[i][0] + bia.x;
    o.y = acc[i][1] + bia.y;
    o.z = acc[i][2] + bia.z;
    o.w = acc[i][3] + bia.w;
    *(float4*)(C + (long long)(bm + ty*4 + i) * N + bn + tx*4) = o;
  }
}

// ============================================================
// Tiled fp32 GEMM, C[M,N] = A[M,K] * B[K,N], batched over blockIdx.z (no bias)
// ============================================================
__global__ __launch_bounds__(256)
void gemm_nn(const float* __restrict__ A, const float* __restrict__ B,
             float* __restrict__ C,
             int M, int N, int K,
             long long sA, long long sB, long long sC) {
  __shared__ float As[16][68];
  __shared__ float Bs[16][68];
  const int tid = threadIdx.x;
  const int tx = tid & 15, ty = tid >> 4;
  const int bm = blockIdx.y * 64, bn = blockIdx.x * 64;
  const long long z = blockIdx.z;
  A += z * sA; B += z * sB; C += z * sC;
  const int lr = tid >> 2;          // 0..63 (A row within tile)
  const int lk = (tid & 3) << 2;    // 0,4,8,12 (A k within tile)
  const int br = tid >> 4;          // 0..15 (B k-row within tile)
  const int bc = (tid & 15) << 2;   // 0..60 (B col within tile)
  const float* Ap = A + (long long)(bm + lr) * K + lk;
  float acc[4][4] = {};
  for (int k0 = 0; k0 < K; k0 += 16) {
    float4 a4 = *(const float4*)(Ap + k0);
    float4 b4 = *(const float4*)(B + (long long)(k0 + br) * N + bn + bc);
    As[lk+0][lr]=a4.x; As[lk+1][lr]=a4.y; As[lk+2][lr]=a4.z; As[lk+3][lr]=a4.w;
    *(float4*)&Bs[br][bc] = b4;
    __syncthreads();
#pragma unroll
    for (int kk = 0; kk < 16; kk++) {
      float4 a = *(const float4*)&As[kk][ty*4];
      float4 b = *(const float4*)&Bs[kk][tx*4];
      float ar[4] = {a.x, a.y, a.z, a.w};
      float br2[4] = {b.x, b.y, b.z, b.w};
#pragma unroll
      for (int i = 0; i < 4; i++)
#pragma unroll
        for (int j = 0; j < 4; j++)
          acc[i][j] += ar[i] * br2[j];
    }
    __syncthreads();
  }
#pragma unroll
  for (int i = 0; i < 4; i++) {
    float4 o = make_float4(acc[i][0], acc[i][1], acc[i][2], acc[i][3]);
    *(float4*)(C + (long long)(bm + ty*4 + i) * N + bn + tx*4) = o;
  }
}

// ============================================================
// Phase normalization, in place: rows of 1024 where [0:512]=re, [512:1024]=im
// becomes [cos(atan2(im,re)) | sin(atan2(im,re))] == [re/r | im/r].
// Uq and Uk are contiguous in ws so one launch covers both (n_rows = 16384).
// ============================================================
__global__ __launch_bounds__(256)
void phase_norm(float* __restrict__ U, long long n_rows) {
  long long idx = (long long)blockIdx.x * blockDim.x + threadIdx.x;
  if (idx >= n_rows * N_HALF) return;
  long long row = idx >> 9;       // / 512
  int j = (int)(idx & (N_HALF - 1));
  float* p = U + row * D_MODEL;
  float re = p[j], im = p[j + N_HALF];
  float n2 = re * re + im * im;
  float cr, sr;
  if (n2 > 0.f) {
    float inv = 1.0f / sqrtf(n2);
    cr = re * inv; sr = im * inv;
  } else {            // atan2(0,0)=0 -> cos=1, sin=0 (match reference)
    cr = 1.0f; sr = 0.0f;
  }
  p[j] = cr; p[j + N_HALF] = sr;
}

// ============================================================
// Zero the sync-stat accumulators (avoid hipMemsetAsync in captured region).
// ============================================================
__global__ __launch_bounds__(256)
void zero_stats(float* __restrict__ p, int n) {
  int i = blockIdx.x * 256 + threadIdx.x;
  if (i < n) p[i] = 0.f;
}

// ============================================================
// Chaotic scores: per batch (blockIdx.z), tile (64q x 64k):
//   scores = (Q . K^T)/32 ; sync = (Uq . Uk^T)/512
//   t = tanh(scores); chaotic = scores + pc*sync + bif*t*(1-t)
// Writes chaotic to Cc; accumulates per-q-row sum(sync), sum(sync^2) via
// wave-level shuffle reduction + 1 atomic per row per (64-wide) k-tile.
// ============================================================
__global__ __launch_bounds__(256)
void chaotic_kernel(const float* __restrict__ Q, const float* __restrict__ Kt,
                    const float* __restrict__ Uq, const float* __restrict__ Uk,
                    float* __restrict__ Cc,
                    float* __restrict__ ssum, float* __restrict__ ssq,
                    const float* __restrict__ bif_p, const float* __restrict__ pc_p) {
  __shared__ float Qs[16][68];
  __shared__ float Ks[16][68];
  __shared__ float Us[16][68];
  __shared__ float Ws[16][68];
  const int tid = threadIdx.x;
  const int tx = tid & 15, ty = tid >> 4;
  const int bm = blockIdx.y * 64, bn = blockIdx.x * 64;
  const long long z = blockIdx.z;
  const long long tS = (long long)S_LEN * D_MODEL;
  Q  += z * tS; Kt += z * tS; Uq += z * tS; Uk += z * tS;
  Cc += z * (long long)S_LEN * S_LEN;
  const int lr = tid >> 2;
  const int lk = (tid & 3) << 2;
  const float* Qp = Q  + (long long)(bm + lr) * D_MODEL + lk;
  const float* Kp = Kt + (long long)(bn + lr) * D_MODEL + lk;
  const float* Up = Uq + (long long)(bm + lr) * D_MODEL + lk;
  const float* Vp = Uk + (long long)(bn + lr) * D_MODEL + lk;
  float acc1[4][4] = {};
  float acc2[4][4] = {};
  for (int k0 = 0; k0 < D_MODEL; k0 += 16) {
    float4 q4 = *(const float4*)(Qp + k0);
    float4 k4 = *(const float4*)(Kp + k0);
    float4 u4 = *(const float4*)(Up + k0);
    float4 w4 = *(const float4*)(Vp + k0);
    Qs[lk+0][lr]=q4.x; Qs[lk+1][lr]=q4.y; Qs[lk+2][lr]=q4.z; Qs[lk+3][lr]=q4.w;
    Ks[lk+0][lr]=k4.x; Ks[lk+1][lr]=k4.y; Ks[lk+2][lr]=k4.z; Ks[lk+3][lr]=k4.w;
    Us[lk+0][lr]=u4.x; Us[lk+1][lr]=u4.y; Us[lk+2][lr]=u4.z; Us[lk+3][lr]=u4.w;
    Ws[lk+0][lr]=w4.x; Ws[lk+1][lr]=w4.y; Ws[lk+2][lr]=w4.z; Ws[lk+3][lr]=w4.w;
    __syncthreads();
#pragma unroll
    for (int kk = 0; kk < 16; kk++) {
      float4 a = *(const float4*)&Qs[kk][ty*4];
      float4 b = *(const float4*)&Ks[kk][tx*4];
      float4 c = *(const float4*)&Us[kk][ty*4];
      float4 d = *(const float4*)&Ws[kk][tx*4];
      float ar[4] = {a.x,a.y,a.z,a.w}, br[4] = {b.x,b.y,b.z,b.w};
      float cr[4] = {c.x,c.y,c.z,c.w}, dr[4] = {d.x,d.y,d.z,d.w};
#pragma unroll
      for (int i = 0; i < 4; i++)
#pragma unroll
        for (int j = 0; j < 4; j++) {
          acc1[i][j] += ar[i] * br[j];
          acc2[i][j] += cr[i] * dr[j];
        }
    }
    __syncthreads();
  }
  const float bif = *bif_p;
  const float pc  = *pc_p;
  float rsum[4] = {}, rsq[4] = {};
#pragma unroll
  for (int i = 0; i < 4; i++) {
    float4 o;
    float oo[4];
#pragma unroll
    for (int j = 0; j < 4; j++) {
      float sc = acc1[i][j] * 0.03125f;            // / sqrt(1024)
      float sy = acc2[i][j] * (1.0f / 512.0f);     // / HALF
      float t  = tanhf(sc);
      oo[j] = sc + pc * sy + bif * t * (1.0f - t);
      rsum[i] += sy;
      rsq[i]  += sy * sy;
    }
    o.x = oo[0]; o.y = oo[1]; o.z = oo[2]; o.w = oo[3];
    *(float4*)(Cc + (long long)(bm + ty*4 + i) * S_LEN + bn + tx*4) = o;
  }
  // reduce across tx (lanes within 16-lane groups of the wave)
#pragma unroll
  for (int m = 1; m < 16; m <<= 1) {
#pragma unroll
    for (int i = 0; i < 4; i++) {
      rsum[i] += __shfl_xor(rsum[i], m);
      rsq[i]  += __shfl_xor(rsq[i], m);
    }
  }
  if (tx == 0) {
    long long base = z * S_LEN + bm + ty*4;
#pragma unroll
    for (int i = 0; i < 4; i++) {
      atomicAdd(&ssum[base + i], rsum[i]);
      atomicAdd(&ssq[base + i],  rsq[i]);
    }
  }
}

// ============================================================
// Row softmax in place, one block (256 thr) per row of 2048.
// ============================================================
__global__ __launch_bounds__(256)
void softmax_kernel(float* __restrict__ Cc) {
  const long long row = (long long)blockIdx.y * S_LEN + blockIdx.x;
  float* p = Cc + row * S_LEN;
  const int tid = threadIdx.x;
  float v[8];
  float m = -3.402823466e+38f;
#pragma unroll
  for (int i = 0; i < 8; i++) { v[i] = p[tid + i*256]; m = fmaxf(m, v[i]); }
#pragma unroll
  for (int mask = 1; mask < 64; mask <<= 1) m = fmaxf(m, __shfl_xor(m, mask));
  __shared__ float red[8];
  if ((tid & 63) == 0) red[tid >> 6] = m;
  __syncthreads();
  m = fmaxf(fmaxf(red[0], red[1]), fmaxf(red[2], red[3]));
  float s = 0.f;
#pragma unroll
  for (int i = 0; i < 8; i++) { v[i] = expf(v[i] - m); s += v[i]; }
#pragma unroll
  for (int mask = 1; mask < 64; mask <<= 1) s += __shfl_xor(s, mask);
  __syncthreads();
  if ((tid & 63) == 0) red[4 + (tid >> 6)] = s;
  __syncthreads();
  s = red[4] + red[5] + red[6] + red[7];
  float inv = 1.0f / s;
#pragma unroll
  for (int i = 0; i < 8; i++) p[tid + i*256] = v[i] * inv;
}

// ============================================================
// sync_loss = 0.01 * mean over 8192 rows of (sumsq - sum^2/N)/(N-1)
// ============================================================
__global__ __launch_bounds__(1024)
void syncloss_kernel(const float* __restrict__ ssum, const float* __restrict__ ssq,
                     float* __restrict__ out) {
  const int tid = threadIdx.x;
  float acc = 0.f;
  for (int r = tid; r < N_BATCH * S_LEN; r += 1024) {
    float su = ssum[r], sq = ssq[r];
    float var = (sq - su * su * (1.0f / 2048.0f)) * (1.0f / 2047.0f);
    acc += var;
  }
#pragma unroll
  for (int mask = 1; mask < 64; mask <<= 1) acc += __shfl_xor(acc, mask);
  __shared__ float red[16];
  if ((tid & 63) == 0) red[tid >> 6] = acc;
  __syncthreads();
  if (tid == 0) {
    float t = 0.f;
#pragma unroll
    for (int k = 0; k < 16; k++) t += red[k];
    out[0] = 0.01f * (t / (float)(N_BATCH * S_LEN));
  }
}

extern "C" void kernel_launch(void* const* d_in, const int* in_sizes, int n_in,
                              void* d_out, int out_size, void* d_ws, size_t ws_size,
                              hipStream_t stream) {
  const float* x    = (const float*)d_in[0];
  const float* Wq   = (const float*)d_in[1];
  const float* bq   = (const float*)d_in[2];
  const float* Wk   = (const float*)d_in[3];
  const float* bk   = (const float*)d_in[4];
  const float* Wv   = (const float*)d_in[5];
  const float* bv   = (const float*)d_in[6];
  const float* Wp   = (const float*)d_in[7];
  const float* bp   = (const float*)d_in[8];
  const float* Wo   = (const float*)d_in[9];
  const float* bo   = (const float*)d_in[10];
  const float* bifp = (const float*)d_in[11];
  const float* pcp  = (const float*)d_in[12];
  float* out = (float*)d_out;

  const long long NROW = (long long)N_BATCH * S_LEN;   // 8192
  const long long TD   = NROW * D_MODEL;               // 8,388,608 floats

  // Workspace layout (peak 201.4 MB):
  //   buf0: Q      -> later V
  //   buf1: K      -> later av
  //   buf2: Uq
  //   buf3: Uk
  //   Cc:   chaotic scores (B*S*S)
  //   ssum/ssq: per-row sync stats
  float* ws   = (float*)d_ws;
  float* buf0 = ws;
  float* buf1 = buf0 + TD;
  float* buf2 = buf1 + TD;
  float* buf3 = buf2 + TD;
  float* Cc   = buf3 + TD;                               // B*S*S floats
  float* ssum = Cc + (long long)N_BATCH * S_LEN * S_LEN; // 8192
  float* ssq  = ssum + NROW;                             // 8192

  dim3 blk(256);
  dim3 gproj(D_MODEL / 64, (int)(NROW / 64), 1);   // 16 x 128

  // Q = x @ Wq^T + bq ; K = x @ Wk^T + bk
  gemm_nt<<<gproj, blk, 0, stream>>>(x, Wq, bq, buf0, (int)NROW, D_MODEL, D_MODEL, 0, 0, 0);
  gemm_nt<<<gproj, blk, 0, stream>>>(x, Wk, bk, buf1, (int)NROW, D_MODEL, D_MODEL, 0, 0, 0);
  // Phase features: pf = {Q,K} @ Wp^T + bp (into Uq/Uk), then normalize in place
  gemm_nt<<<gproj, blk, 0, stream>>>(buf0, Wp, bp, buf2, (int)NROW, D_MODEL, D_MODEL, 0, 0, 0);
  gemm_nt<<<gproj, blk, 0, stream>>>(buf1, Wp, bp, buf3, (int)NROW, D_MODEL, D_MODEL, 0, 0, 0);
  {
    long long tot = 2 * NROW * N_HALF;
    int nb = (int)((tot + 255) / 256);
    phase_norm<<<nb, blk, 0, stream>>>(buf2, 2 * NROW);
  }
  // Zero sync stats (kernel, not hipMemsetAsync, to stay graph-capture-safe)
  zero_stats<<<(int)((2 * NROW + 255) / 256), blk, 0, stream>>>(ssum, (int)(2 * NROW));
  // Chaotic scores + sync stats
  chaotic_kernel<<<dim3(S_LEN/64, S_LEN/64, N_BATCH), blk, 0, stream>>>(
      buf0, buf1, buf2, buf3, Cc, ssum, ssq, bifp, pcp);
  // Softmax in place
  softmax_kernel<<<dim3(S_LEN, N_BATCH), blk, 0, stream>>>(Cc);
  // V = x @ Wv^T + bv  (overwrites Q, no longer needed)
  gemm_nt<<<gproj, blk, 0, stream>>>(x, Wv, bv, buf0, (int)NROW, D_MODEL, D_MODEL, 0, 0, 0);
  // av = P @ V   (batched NN gemm; overwrites K)
  gemm_nn<<<dim3(D_MODEL/64, S_LEN/64, N_BATCH), blk, 0, stream>>>(
      Cc, buf0, buf1, S_LEN, D_MODEL, S_LEN,
      (long long)S_LEN * S_LEN, (long long)S_LEN * D_MODEL, (long long)S_LEN * D_MODEL);
  // out = av @ Wo^T + bo
  gemm_nt<<<gproj, blk, 0, stream>>>(buf1, Wo, bo, out, (int)NROW, D_MODEL, D_MODEL, 0, 0, 0);
  // sync_loss
  syncloss_kernel<<<1, 1024, 0, stream>>>(ssum, ssq, out + TD);
}

// Round 3
// 624.422 us; speedup vs baseline: 4.5162x; 4.5162x over previous
//
#include <hip/hip_runtime.h>
#include <hip/hip_bf16.h>
#include <math.h>

#define S_LEN 2048
#define D_MODEL 1024
#define N_BATCH 4
#define N_HALF 512

typedef unsigned short u16;
typedef __attribute__((ext_vector_type(8))) short bf16x8;
typedef __attribute__((ext_vector_type(4))) float f32x4;

// ---------- helpers ----------
__device__ inline u16 f2bf(float v) {
  __hip_bfloat16 h = __float2bfloat16(v);   // RNE
  return *reinterpret_cast<u16*>(&h);
}
__device__ inline float bf2f(u16 u) {
  __hip_bfloat16 h = *reinterpret_cast<__hip_bfloat16*>(&u);
  return __bfloat162float(h);
}
// async global->LDS, 16B per lane; LDS dest is wave-uniform base + lane*16
__device__ inline void gl2lds16(const void* g, void* l) {
  __builtin_amdgcn_global_load_lds(
      (const __attribute__((address_space(1))) unsigned int*)g,
      (__attribute__((address_space(3))) unsigned int*)l, 16, 0, 0);
}

// ---------- casts ----------
__global__ __launch_bounds__(256)
void cast_bf(const float* __restrict__ src, u16* __restrict__ dst, long long n) {
  long long i = (long long)blockIdx.x * 256 + threadIdx.x;
  if (i < n) dst[i] = f2bf(src[i]);
}
__global__ __launch_bounds__(256)
void cast_split(const float* __restrict__ src, u16* __restrict__ hi,
                u16* __restrict__ lo, long long n) {
  long long i = (long long)blockIdx.x * 256 + threadIdx.x;
  if (i < n) {
    float v = src[i];
    u16 h = f2bf(v);
    hi[i] = h;
    lo[i] = f2bf(v - bf2f(h));
  }
}
__global__ __launch_bounds__(256)
void zero_stats(float* __restrict__ p, int n) {
  int i = blockIdx.x * 256 + threadIdx.x;
  if (i < n) p[i] = 0.f;
}

// ============================================================
// Core MFMA GEMM (NT): C[M,N] = A[M,K] * B[N,K]^T, bf16 in, fp32 acc.
// m97 structure: 128x128 tile, 256 thr (4 waves, 2x2 of 64x64),
// BK=32, global_load_lds width16, LDS row-major [128][32].
// EPI: 0 = bf16 out + bias[col]     (Q, K, pf)
//      1 = bf16 out + bias[row]     (Vt)
//      2 = hi/lo bf16 out, no bias  (av)
//      3 = fp32 out * 1/32          (scores)
//      4 = chaotic: read fp32 C0, combine, write fp32 C0, row stats (sync)
// ============================================================
template<int EPI>
__global__ __launch_bounds__(256)
void mfma_gemm(const u16* __restrict__ A, const u16* __restrict__ B,
               const float* __restrict__ bias,
               void* __restrict__ C0v, void* __restrict__ C1v,
               float* __restrict__ ssum, float* __restrict__ ssq,
               const float* __restrict__ bifp, const float* __restrict__ pcp,
               int N, int K,
               long long sA, long long sB, long long sC) {
  __shared__ u16 As[128 * 32];
  __shared__ u16 Bs[128 * 32];
  const int tid  = threadIdx.x;
  const int wave = tid >> 6;
  const int lane = tid & 63;
  const int quad = lane >> 4;
  const int tc   = lane & 15;
  const int bm = blockIdx.y * 128;
  const int bn = blockIdx.x * 128;
  const long long z = blockIdx.z;

  const int wm = (wave & 1) * 64;
  const int wn = (wave >> 1) * 64;

  f32x4 acc[4][4];
#pragma unroll
  for (int i = 0; i < 4; i++)
#pragma unroll
    for (int j = 0; j < 4; j++) acc[i][j] = (f32x4){0.f, 0.f, 0.f, 0.f};

  // staging addresses: wave stages rows [wave*32, wave*32+32) of each tile
  const int srow = wave * 32 + (lane >> 2);
  const int scol = (lane & 3) * 8;
  const u16* ga = A + z * sA + (long long)(bm + srow) * K + scol;
  const u16* gb = B + z * sB + (long long)(bn + srow) * K + scol;
  u16* lA0 = As + (wave * 32) * 32;
  u16* lA1 = As + (wave * 32 + 16) * 32;
  u16* lB0 = Bs + (wave * 32) * 32;
  u16* lB1 = Bs + (wave * 32 + 16) * 32;
  const long long r16K = 16LL * K;

  for (int k0 = 0; k0 < K; k0 += 32) {
    gl2lds16(ga,        lA0);
    gl2lds16(ga + r16K, lA1);
    gl2lds16(gb,        lB0);
    gl2lds16(gb + r16K, lB1);
    ga += 32; gb += 32;
    __syncthreads();
    bf16x8 af[4], bg[4];
#pragma unroll
    for (int i = 0; i < 4; i++)
      af[i] = *(const bf16x8*)(As + (wm + i * 16 + tc) * 32 + quad * 8);
#pragma unroll
    for (int j = 0; j < 4; j++)
      bg[j] = *(const bf16x8*)(Bs + (wn + j * 16 + tc) * 32 + quad * 8);
#pragma unroll
    for (int i = 0; i < 4; i++)
#pragma unroll
      for (int j = 0; j < 4; j++)
        acc[i][j] = __builtin_amdgcn_mfma_f32_16x16x32_bf16(af[i], bg[j], acc[i][j], 0, 0, 0);
    __syncthreads();
  }

  // ---------- epilogue ----------
  float bifv = 0.f, pcv = 0.f;
  float rsum[4][4], rsq[4][4];
  if (EPI == 4) {
    bifv = *bifp; pcv = *pcp;
#pragma unroll
    for (int i = 0; i < 4; i++)
#pragma unroll
      for (int r = 0; r < 4; r++) { rsum[i][r] = 0.f; rsq[i][r] = 0.f; }
  }

#pragma unroll
  for (int i = 0; i < 4; i++) {
    const int row0 = bm + wm + i * 16 + quad * 4;
#pragma unroll
    for (int j = 0; j < 4; j++) {
      const int col = bn + wn + j * 16 + tc;
#pragma unroll
      for (int r = 0; r < 4; r++) {
        float v = acc[i][j][r];
        long long idx = (long long)(row0 + r) * N + col;
        if (EPI == 0) {
          u16* C = (u16*)C0v + z * sC;
          C[idx] = f2bf(v + bias[col]);
        } else if (EPI == 1) {
          u16* C = (u16*)C0v + z * sC;
          C[idx] = f2bf(v + bias[row0 + r]);
        } else if (EPI == 2) {
          u16* Ch = (u16*)C0v + z * sC;
          u16* Cl = (u16*)C1v + z * sC;
          u16 h = f2bf(v);
          Ch[idx] = h;
          Cl[idx] = f2bf(v - bf2f(h));
        } else if (EPI == 3) {
          float* C = (float*)C0v + z * sC;
          C[idx] = v * 0.03125f;   // / sqrt(1024)
        } else if (EPI == 4) {
          float* C = (float*)C0v + z * sC;
          float sc = C[idx];
          float sy = v * (1.0f / 512.0f);
          float t  = tanhf(sc);
          C[idx] = sc + pcv * sy + bifv * t * (1.0f - t);
          rsum[i][r] += sy;
          rsq[i][r]  += sy * sy;
        }
      }
    }
  }

  if (EPI == 4) {
    // reduce over the 16 lanes of each quad (cols), then 1 atomic per row
#pragma unroll
    for (int m = 1; m < 16; m <<= 1) {
#pragma unroll
      for (int i = 0; i < 4; i++)
#pragma unroll
        for (int r = 0; r < 4; r++) {
          rsum[i][r] += __shfl_xor(rsum[i][r], m);
          rsq[i][r]  += __shfl_xor(rsq[i][r], m);
        }
    }
    if (tc == 0) {
#pragma unroll
      for (int i = 0; i < 4; i++)
#pragma unroll
        for (int r = 0; r < 4; r++) {
          long long rr = z * S_LEN + bm + wm + i * 16 + quad * 4 + r;
          atomicAdd(&ssum[rr], rsum[i][r]);
          atomicAdd(&ssq[rr],  rsq[i][r]);
        }
    }
  }
}

// ============================================================
// Split-precision output GEMM: out = (Ah+Al)(Bh+Bl)^T + bias, fp32 out.
// 3 MFMAs per frag step (drop Al*Bl). Same tile structure.
// ============================================================
__global__ __launch_bounds__(256)
void mfma_gemm_out3(const u16* __restrict__ Ah, const u16* __restrict__ Al,
                    const u16* __restrict__ Bh, const u16* __restrict__ Bl,
                    const float* __restrict__ bias, float* __restrict__ C,
                    int N, int K) {
  __shared__ u16 Ash[128 * 32];
  __shared__ u16 Asl[128 * 32];
  __shared__ u16 Bsh[128 * 32];
  __shared__ u16 Bsl[128 * 32];
  const int tid  = threadIdx.x;
  const int wave = tid >> 6;
  const int lane = tid & 63;
  const int quad = lane >> 4;
  const int tc   = lane & 15;
  const int bm = blockIdx.y * 128;
  const int bn = blockIdx.x * 128;
  const int wm = (wave & 1) * 64;
  const int wn = (wave >> 1) * 64;

  f32x4 acc[4][4];
#pragma unroll
  for (int i = 0; i < 4; i++)
#pragma unroll
    for (int j = 0; j < 4; j++) acc[i][j] = (f32x4){0.f, 0.f, 0.f, 0.f};

  const int srow = wave * 32 + (lane >> 2);
  const int scol = (lane & 3) * 8;
  long long aoff = (long long)(bm + srow) * K + scol;
  long long boff = (long long)(bn + srow) * K + scol;
  const u16 *gah = Ah + aoff, *gal = Al + aoff;
  const u16 *gbh = Bh + boff, *gbl = Bl + boff;
  u16* l0 = (u16*)0;
  const int wbase = (wave * 32) * 32;
  const long long r16K = 16LL * K;

  for (int k0 = 0; k0 < K; k0 += 32) {
    gl2lds16(gah,        Ash + wbase);
    gl2lds16(gah + r16K, Ash + wbase + 512);
    gl2lds16(gal,        Asl + wbase);
    gl2lds16(gal + r16K, Asl + wbase + 512);
    gl2lds16(gbh,        Bsh + wbase);
    gl2lds16(gbh + r16K, Bsh + wbase + 512);
    gl2lds16(gbl,        Bsl + wbase);
    gl2lds16(gbl + r16K, Bsl + wbase + 512);
    gah += 32; gal += 32; gbh += 32; gbl += 32;
    __syncthreads();
    bf16x8 ah[4], al[4], bh[4], bl[4];
#pragma unroll
    for (int i = 0; i < 4; i++) {
      int o = (wm + i * 16 + tc) * 32 + quad * 8;
      ah[i] = *(const bf16x8*)(Ash + o);
      al[i] = *(const bf16x8*)(Asl + o);
    }
#pragma unroll
    for (int j = 0; j < 4; j++) {
      int o = (wn + j * 16 + tc) * 32 + quad * 8;
      bh[j] = *(const bf16x8*)(Bsh + o);
      bl[j] = *(const bf16x8*)(Bsl + o);
    }
#pragma unroll
    for (int i = 0; i < 4; i++)
#pragma unroll
      for (int j = 0; j < 4; j++) {
        acc[i][j] = __builtin_amdgcn_mfma_f32_16x16x32_bf16(ah[i], bh[j], acc[i][j], 0, 0, 0);
        acc[i][j] = __builtin_amdgcn_mfma_f32_16x16x32_bf16(ah[i], bl[j], acc[i][j], 0, 0, 0);
        acc[i][j] = __builtin_amdgcn_mfma_f32_16x16x32_bf16(al[i], bh[j], acc[i][j], 0, 0, 0);
      }
    __syncthreads();
  }
  (void)l0;
#pragma unroll
  for (int i = 0; i < 4; i++) {
    const int row0 = bm + wm + i * 16 + quad * 4;
#pragma unroll
    for (int j = 0; j < 4; j++) {
      const int col = bn + wn + j * 16 + tc;
#pragma unroll
      for (int r = 0; r < 4; r++)
        C[(long long)(row0 + r) * N + col] = acc[i][j][r] + bias[col];
    }
  }
}

// ============================================================
// Phase normalize in place on bf16 pf rows: [re|im] -> [re/r | im/r]
// ============================================================
__global__ __launch_bounds__(256)
void phase_norm_bf(u16* __restrict__ U, long long n_rows) {
  long long idx = (long long)blockIdx.x * 256 + threadIdx.x;
  if (idx >= n_rows * N_HALF) return;
  long long row = idx >> 9;
  int j = (int)(idx & (N_HALF - 1));
  u16* p = U + row * D_MODEL;
  float re = bf2f(p[j]), im = bf2f(p[j + N_HALF]);
  float n2 = re * re + im * im;
  float cr = 1.f, sr = 0.f;
  if (n2 > 0.f) {
    float inv = 1.0f / sqrtf(n2);
    cr = re * inv; sr = im * inv;
  }
  p[j] = f2bf(cr); p[j + N_HALF] = f2bf(sr);
}

// ============================================================
// Row softmax: fp32 in (chaotic), bf16 out (attn). 1 block / row.
// ============================================================
__global__ __launch_bounds__(256)
void softmax_bf(const float* __restrict__ Cc, u16* __restrict__ P) {
  const long long row = (long long)blockIdx.y * S_LEN + blockIdx.x;
  const float* p = Cc + row * S_LEN;
  u16* q = P + row * S_LEN;
  const int tid = threadIdx.x;
  float v[8];
  float m = -3.402823466e+38f;
#pragma unroll
  for (int i = 0; i < 8; i++) { v[i] = p[tid + i * 256]; m = fmaxf(m, v[i]); }
#pragma unroll
  for (int mask = 1; mask < 64; mask <<= 1) m = fmaxf(m, __shfl_xor(m, mask));
  __shared__ float red[8];
  if ((tid & 63) == 0) red[tid >> 6] = m;
  __syncthreads();
  m = fmaxf(fmaxf(red[0], red[1]), fmaxf(red[2], red[3]));
  float s = 0.f;
#pragma unroll
  for (int i = 0; i < 8; i++) { v[i] = expf(v[i] - m); s += v[i]; }
#pragma unroll
  for (int mask = 1; mask < 64; mask <<= 1) s += __shfl_xor(s, mask);
  __syncthreads();
  if ((tid & 63) == 0) red[4 + (tid >> 6)] = s;
  __syncthreads();
  s = red[4] + red[5] + red[6] + red[7];
  float inv = 1.0f / s;
#pragma unroll
  for (int i = 0; i < 8; i++) q[tid + i * 256] = f2bf(v[i] * inv);
}

// ============================================================
// sync_loss
// ============================================================
__global__ __launch_bounds__(1024)
void syncloss_kernel(const float* __restrict__ ssum, const float* __restrict__ ssq,
                     float* __restrict__ out) {
  const int tid = threadIdx.x;
  float acc = 0.f;
  for (int r = tid; r < N_BATCH * S_LEN; r += 1024) {
    float su = ssum[r], sq = ssq[r];
    acc += (sq - su * su * (1.0f / 2048.0f)) * (1.0f / 2047.0f);
  }
#pragma unroll
  for (int mask = 1; mask < 64; mask <<= 1) acc += __shfl_xor(acc, mask);
  __shared__ float red[16];
  if ((tid & 63) == 0) red[tid >> 6] = acc;
  __syncthreads();
  if (tid == 0) {
    float t = 0.f;
#pragma unroll
    for (int k = 0; k < 16; k++) t += red[k];
    out[0] = 0.01f * (t / (float)(N_BATCH * S_LEN));
  }
}

extern "C" void kernel_launch(void* const* d_in, const int* in_sizes, int n_in,
                              void* d_out, int out_size, void* d_ws, size_t ws_size,
                              hipStream_t stream) {
  const float* x    = (const float*)d_in[0];
  const float* Wq   = (const float*)d_in[1];
  const float* bq   = (const float*)d_in[2];
  const float* Wk   = (const float*)d_in[3];
  const float* bk   = (const float*)d_in[4];
  const float* Wv   = (const float*)d_in[5];
  const float* bv   = (const float*)d_in[6];
  const float* Wp   = (const float*)d_in[7];
  const float* bp   = (const float*)d_in[8];
  const float* Wo   = (const float*)d_in[9];
  const float* bo   = (const float*)d_in[10];
  const float* bifp = (const float*)d_in[11];
  const float* pcp  = (const float*)d_in[12];
  float* out = (float*)d_out;

  const long long NROW = (long long)N_BATCH * S_LEN;   // 8192
  const long long TD   = NROW * D_MODEL;               // 8,388,608
  const long long WSZ  = (long long)D_MODEL * D_MODEL; // 1,048,576

  // workspace layout (~180 MB)
  u16* xbf = (u16*)d_ws;            // TD
  u16* wqb = xbf + TD;              // WSZ each
  u16* wkb = wqb + WSZ;
  u16* wvb = wkb + WSZ;
  u16* wpb = wvb + WSZ;
  u16* woh = wpb + WSZ;
  u16* wol = woh + WSZ;
  u16* Qbf = wol + WSZ;             // TD
  u16* Kbf = Qbf + TD;              // TD
  u16* pfQ = Kbf + TD;              // TD  (-> Uq, later av_hi)
  u16* pfK = pfQ + TD;              // TD  (-> Uk, later av_lo)
  u16* Vt  = pfK + TD;              // TD  ([b][d][s])
  float* Cc = (float*)(Vt + TD);    // B*S*S fp32
  float* ssum = Cc + (long long)N_BATCH * S_LEN * S_LEN;
  float* ssq  = ssum + NROW;
  u16* attn = Qbf;                  // overlays Q+K after scores (16.8M u16)
  u16* avh = pfQ;                   // overlays Uq after chaotic
  u16* avl = pfK;

  dim3 blk(256);
  const long long sQ = (long long)S_LEN * D_MODEL;   // 2048*1024
  const long long sS = (long long)S_LEN * S_LEN;     // 2048*2048

  // casts
  cast_bf<<<(int)(TD / 256), blk, 0, stream>>>(x, xbf, TD);
  cast_bf<<<(int)(WSZ / 256), blk, 0, stream>>>(Wq, wqb, WSZ);
  cast_bf<<<(int)(WSZ / 256), blk, 0, stream>>>(Wk, wkb, WSZ);
  cast_bf<<<(int)(WSZ / 256), blk, 0, stream>>>(Wv, wvb, WSZ);
  cast_bf<<<(int)(WSZ / 256), blk, 0, stream>>>(Wp, wpb, WSZ);
  cast_split<<<(int)(WSZ / 256), blk, 0, stream>>>(Wo, woh, wol, WSZ);

  // Q = x@Wq^T+bq, K = x@Wk^T+bk   (bf16 out)
  mfma_gemm<0><<<dim3(8, 64, 1), blk, 0, stream>>>(xbf, wqb, bq, Qbf, nullptr,
      nullptr, nullptr, nullptr, nullptr, D_MODEL, D_MODEL, 0, 0, 0);
  mfma_gemm<0><<<dim3(8, 64, 1), blk, 0, stream>>>(xbf, wkb, bk, Kbf, nullptr,
      nullptr, nullptr, nullptr, nullptr, D_MODEL, D_MODEL, 0, 0, 0);
  // Vt[b][d][s] = Wv@x_b^T + bv[d]  (row bias, bf16 out)
  mfma_gemm<1><<<dim3(16, 8, N_BATCH), blk, 0, stream>>>(wvb, xbf, bv, Vt, nullptr,
      nullptr, nullptr, nullptr, nullptr, S_LEN, D_MODEL, 0, sQ, (long long)D_MODEL * S_LEN);
  // pf = {Q,K}@Wp^T + bp (bf16 out), then phase-normalize in place -> Uq,Uk
  mfma_gemm<0><<<dim3(8, 64, 1), blk, 0, stream>>>(Qbf, wpb, bp, pfQ, nullptr,
      nullptr, nullptr, nullptr, nullptr, D_MODEL, D_MODEL, 0, 0, 0);
  mfma_gemm<0><<<dim3(8, 64, 1), blk, 0, stream>>>(Kbf, wpb, bp, pfK, nullptr,
      nullptr, nullptr, nullptr, nullptr, D_MODEL, D_MODEL, 0, 0, 0);
  phase_norm_bf<<<(int)(2 * NROW * N_HALF / 256), blk, 0, stream>>>(pfQ, 2 * NROW);
  zero_stats<<<(int)((2 * NROW + 255) / 256), blk, 0, stream>>>(ssum, (int)(2 * NROW));

  // scores = Q@K^T / 32 (fp32 -> Cc)
  mfma_gemm<3><<<dim3(16, 16, N_BATCH), blk, 0, stream>>>(Qbf, Kbf, nullptr, Cc, nullptr,
      nullptr, nullptr, nullptr, nullptr, S_LEN, D_MODEL, sQ, sQ, sS);
  // chaotic = scores + pc*sync + bif*t*(1-t); sync = Uq@Uk^T/512; + row stats
  mfma_gemm<4><<<dim3(16, 16, N_BATCH), blk, 0, stream>>>(pfQ, pfK, nullptr, Cc, nullptr,
      ssum, ssq, bifp, pcp, S_LEN, D_MODEL, sQ, sQ, sS);
  // softmax (fp32 in, bf16 attn out; overlays Q/K)
  softmax_bf<<<dim3(S_LEN, N_BATCH), blk, 0, stream>>>(Cc, attn);
  // av = attn @ Vt^T  -> hi/lo bf16 (overlays Uq/Uk)
  mfma_gemm<2><<<dim3(8, 16, N_BATCH), blk, 0, stream>>>(attn, Vt, nullptr, avh, avl,
      nullptr, nullptr, nullptr, nullptr, D_MODEL, S_LEN, sS, (long long)D_MODEL * S_LEN, sQ);
  // out = (avh+avl)@(Woh+Wol)^T + bo   (fp32, split 3-MFMA)
  mfma_gemm_out3<<<dim3(8, 64, 1), blk, 0, stream>>>(avh, avl, woh, wol, bo, out,
      D_MODEL, D_MODEL);
  // sync_loss
  syncloss_kernel<<<1, 1024, 0, stream>>>(ssum, ssq, out + TD);
}